// Round 5
// baseline (884.487 us; speedup 1.0000x reference)
//
#include <hip/hip_runtime.h>

// ---------------------------------------------------------------------------
// GCN forward, CSR-sorted aggregation (no atomics in hot path):
//   build: deg count -> prefix sum (rowptr) -> counting-sort fill (src_sorted)
//   3x: GEMM (bf16-split MFMA, ~2^-17 accuracy) -> agg (wave/node float4 gather)
//   pool head: per-node dot -> nodeval[N] -> per-graph segmented block reduce
// All feature matrices [N,128] row-major fp32.
// ---------------------------------------------------------------------------

typedef __attribute__((ext_vector_type(8))) short bf16x8;
typedef __attribute__((ext_vector_type(4))) float f32x4;

__device__ __forceinline__ unsigned short f32_to_bf16_rne(float f) {
    unsigned u = __float_as_uint(f);
    unsigned r = u + 0x7FFF + ((u >> 16) & 1);
    return (unsigned short)(r >> 16);
}
__device__ __forceinline__ float bf16_to_f32(unsigned short h) {
    return __uint_as_float(((unsigned)h) << 16);
}

__global__ __launch_bounds__(256) void count_deg_kernel(const int* __restrict__ col,
                                                        int* __restrict__ deg, int E) {
    int e = blockIdx.x * 256 + threadIdx.x;
    if (e < E) atomicAdd(&deg[col[e]], 1);
}

// per-block exclusive scan of deg (1024 elems/block) -> rowptr; block totals out
__global__ __launch_bounds__(256) void scan1_kernel(const int* __restrict__ deg,
                                                    int* __restrict__ rowptr,
                                                    int* __restrict__ blockSums, int N) {
    __shared__ int ts[256];
    const int t = threadIdx.x;
    const int base = blockIdx.x * 1024 + t * 4;
    int v0 = 0, v1 = 0, v2 = 0, v3 = 0;
    if (base + 3 < N) {
        int4 v = *(const int4*)&deg[base];
        v0 = v.x; v1 = v.y; v2 = v.z; v3 = v.w;
    } else {
        if (base + 0 < N) v0 = deg[base + 0];
        if (base + 1 < N) v1 = deg[base + 1];
        if (base + 2 < N) v2 = deg[base + 2];
        if (base + 3 < N) v3 = deg[base + 3];
    }
    const int tot = v0 + v1 + v2 + v3;
    ts[t] = tot;
    __syncthreads();
    for (int off = 1; off < 256; off <<= 1) {
        int add = (t >= off) ? ts[t - off] : 0;
        __syncthreads();
        ts[t] += add;
        __syncthreads();
    }
    const int excl = ts[t] - tot;
    if (base + 0 < N) rowptr[base + 0] = excl;
    if (base + 1 < N) rowptr[base + 1] = excl + v0;
    if (base + 2 < N) rowptr[base + 2] = excl + v0 + v1;
    if (base + 3 < N) rowptr[base + 3] = excl + v0 + v1 + v2;
    if (t == 255) blockSums[blockIdx.x] = ts[255];
}

__global__ __launch_bounds__(128) void scan2_kernel(const int* __restrict__ blockSums,
                                                    int* __restrict__ blockOffs, int B) {
    __shared__ int ts[128];
    const int t = threadIdx.x;
    ts[t] = (t < B) ? blockSums[t] : 0;
    __syncthreads();
    for (int off = 1; off < 128; off <<= 1) {
        int add = (t >= off) ? ts[t - off] : 0;
        __syncthreads();
        ts[t] += add;
        __syncthreads();
    }
    if (t < B) blockOffs[t] = ts[t];
}

__global__ __launch_bounds__(256) void scan3_kernel(int* __restrict__ rowptr,
                                                    const int* __restrict__ blockOffs, int N) {
    int i = blockIdx.x * 256 + threadIdx.x;
    if (i >= N) return;
    int b = i >> 10;
    if (b > 0) rowptr[i] += blockOffs[b - 1];
}

__global__ __launch_bounds__(256) void dinv_kernel(int* __restrict__ degi,
                                                   float* __restrict__ dinv, int N) {
    int n = blockIdx.x * 256 + threadIdx.x;
    if (n < N) dinv[n] = 1.0f / sqrtf((float)degi[n] + 1.0f);  // +1 = self loop
}

// counting-sort fill; rowptr-shift trick: after fill, bucket c = [rowptr[c-1], rowptr[c])
__global__ __launch_bounds__(256) void fill_kernel(const int* __restrict__ ei,
                                                   int* __restrict__ rowptr,
                                                   int* __restrict__ src_sorted, int E) {
    int e = blockIdx.x * 256 + threadIdx.x;
    if (e >= E) return;
    int c = ei[E + e];
    int pos = atomicAdd(&rowptr[c], 1);
    src_sorted[pos] = ei[e];
}

// T = act(H) @ W via bf16-split MFMA: T ~= Hhi*Whi + Hhi*Wlo + Hlo*Whi (rel err ~2^-17)
// Block = 256 thr = 4 waves, 64 rows (16/wave). W staged in LDS pre-swizzled to
// B-fragment order: frag(c,t,lane) = W[c*32 + (lane>>4)*8 + j][t*16 + (lane&15)], j=0..7.
__global__ __launch_bounds__(256) void gemm_mfma_kernel(const float* __restrict__ H,
                                                        const float* __restrict__ W,
                                                        float* __restrict__ T,
                                                        int N, int applyRelu) {
    __shared__ unsigned short Whi[4 * 8 * 64 * 8];   // 32 KB
    __shared__ unsigned short Wlo[4 * 8 * 64 * 8];   // 32 KB
    const int tid = threadIdx.x;

    // stage + split W (coalesced float4 reads, u16 LDS scatter)
    for (int i = tid; i < 4096; i += 256) {
        int k = i >> 5;              // W row
        int n4 = i & 31;             // W col / 4
        float4 w = ((const float4*)W)[i];
        int c = k >> 5;
        int lhi = (k >> 3) & 3;      // quad = (lane>>4)
        int j = k & 7;
        float vals[4] = {w.x, w.y, w.z, w.w};
        #pragma unroll
        for (int m = 0; m < 4; ++m) {
            int col = n4 * 4 + m;
            int t = col >> 4;
            int l = lhi * 16 + (col & 15);
            int idx = (((c * 8 + t) * 64) + l) * 8 + j;
            float v = vals[m];
            unsigned short hi = f32_to_bf16_rne(v);
            unsigned short lo = f32_to_bf16_rne(v - bf16_to_f32(hi));
            Whi[idx] = hi;
            Wlo[idx] = lo;
        }
    }
    __syncthreads();

    const int wv = tid >> 6;
    const int lane = tid & 63;
    const int r0 = blockIdx.x * 64 + wv * 16;
    const int mrow = lane & 15;
    const int kq = lane >> 4;        // quad
    const int grow = r0 + mrow;
    const bool rok = grow < N;

    f32x4 acc[8];
    #pragma unroll
    for (int t = 0; t < 8; ++t) acc[t] = (f32x4){0.f, 0.f, 0.f, 0.f};

    #pragma unroll
    for (int c = 0; c < 4; ++c) {
        float av[8];
        if (rok) {
            const float4* Hp = (const float4*)(H + (size_t)grow * 128 + c * 32 + kq * 8);
            float4 a0 = Hp[0], a1 = Hp[1];
            av[0] = a0.x; av[1] = a0.y; av[2] = a0.z; av[3] = a0.w;
            av[4] = a1.x; av[5] = a1.y; av[6] = a1.z; av[7] = a1.w;
        } else {
            #pragma unroll
            for (int j = 0; j < 8; ++j) av[j] = 0.f;
        }
        bf16x8 ahi, alo;
        #pragma unroll
        for (int j = 0; j < 8; ++j) {
            float v = av[j];
            if (applyRelu) v = fmaxf(v, 0.f);
            unsigned short h = f32_to_bf16_rne(v);
            unsigned short l = f32_to_bf16_rne(v - bf16_to_f32(h));
            ahi[j] = (short)h;
            alo[j] = (short)l;
        }
        #pragma unroll
        for (int t = 0; t < 8; ++t) {
            bf16x8 wh = *(const bf16x8*)&Whi[(((c * 8 + t) * 64) + lane) * 8];
            bf16x8 wl = *(const bf16x8*)&Wlo[(((c * 8 + t) * 64) + lane) * 8];
            acc[t] = __builtin_amdgcn_mfma_f32_16x16x32_bf16(ahi, wh, acc[t], 0, 0, 0);
            acc[t] = __builtin_amdgcn_mfma_f32_16x16x32_bf16(ahi, wl, acc[t], 0, 0, 0);
            acc[t] = __builtin_amdgcn_mfma_f32_16x16x32_bf16(alo, wh, acc[t], 0, 0, 0);
        }
    }

    // epilogue: C/D layout col=lane&15, row=(lane>>4)*4+r
    #pragma unroll
    for (int r = 0; r < 4; ++r) {
        int orow = r0 + kq * 4 + r;
        if (orow < N) {
            float* Tp = T + (size_t)orow * 128 + mrow;
            #pragma unroll
            for (int t = 0; t < 8; ++t) Tp[t * 16] = acc[t][r];
        }
    }
}

// one wave per node, float4 lanes, 2 edges/iter (lanes 0-31 even, 32-63 odd):
// B[n,:] = dinv[n]^2*A[n,:] + bias + sum_e dinv[n]*dinv[s_e]*A[s_e,:]
__global__ __launch_bounds__(256) void agg_kernel(const int* __restrict__ rowptr,
                                                  const int* __restrict__ src,
                                                  const float* __restrict__ dinv,
                                                  const float* __restrict__ A,
                                                  const float* __restrict__ bias,
                                                  float* __restrict__ B, int N) {
    int w = (blockIdx.x * 256 + threadIdx.x) >> 6;
    if (w >= N) return;
    const int lane = threadIdx.x & 63;
    const int half = lane >> 5;
    const int q = lane & 31;
    const int beg = (w > 0) ? rowptr[w - 1] : 0;
    const int end = rowptr[w];
    const float dn = dinv[w];
    const float4* A4 = (const float4*)A;

    float4 acc = make_float4(0.f, 0.f, 0.f, 0.f);
    for (int e = beg + half; e < end; e += 2) {
        int s = src[e];
        float nrm = dn * dinv[s];
        float4 v = A4[(size_t)s * 32 + q];
        acc.x = fmaf(nrm, v.x, acc.x);
        acc.y = fmaf(nrm, v.y, acc.y);
        acc.z = fmaf(nrm, v.z, acc.z);
        acc.w = fmaf(nrm, v.w, acc.w);
    }
    acc.x += __shfl_xor(acc.x, 32);
    acc.y += __shfl_xor(acc.y, 32);
    acc.z += __shfl_xor(acc.z, 32);
    acc.w += __shfl_xor(acc.w, 32);

    if (half == 0) {
        float4 a = A4[(size_t)w * 32 + q];
        float4 bv = ((const float4*)bias)[q];
        float d2 = dn * dn;
        acc.x = fmaf(d2, a.x, acc.x + bv.x);
        acc.y = fmaf(d2, a.y, acc.y + bv.y);
        acc.z = fmaf(d2, a.z, acc.z + bv.z);
        acc.w = fmaf(d2, a.w, acc.w + bv.w);
        ((float4*)B)[(size_t)w * 32 + q] = acc;
    }
}

// one wave per node: nodeval[n] = dot(relu(H[n,:]), lin_w)  (zero atomics)
__global__ __launch_bounds__(256) void nodedot_kernel(const float* __restrict__ H,
                                                      const float* __restrict__ lin_w,
                                                      float* __restrict__ nodeval, int N) {
    int w = (blockIdx.x * 256 + threadIdx.x) >> 6;
    if (w >= N) return;
    const int lane = threadIdx.x & 63;
    float2 v = ((const float2*)(H + (size_t)w * 128))[lane];
    float2 wv = ((const float2*)lin_w)[lane];
    float s = fmaxf(v.x, 0.f) * wv.x + fmaxf(v.y, 0.f) * wv.y;
    #pragma unroll
    for (int o = 32; o > 0; o >>= 1) s += __shfl_xor(s, o);
    if (lane == 0) nodeval[w] = s;
}

__device__ __forceinline__ int lower_bound_dev(const int* __restrict__ a, int n, int key) {
    int lo = 0, hi = n;
    while (lo < hi) {
        int mid = (lo + hi) >> 1;
        if (a[mid] < key) lo = mid + 1; else hi = mid;
    }
    return lo;
}

// one block per graph: out[g] = mean(nodeval[lo:hi]) + lin_b  (batch is sorted)
__global__ __launch_bounds__(256) void segreduce_kernel(const float* __restrict__ nodeval,
                                                        const int* __restrict__ batch,
                                                        const float* __restrict__ lin_b,
                                                        float* __restrict__ out, int N) {
    const int g = blockIdx.x;
    const int lo = lower_bound_dev(batch, N, g);
    const int hi = lower_bound_dev(batch, N, g + 1);
    float acc = 0.f;
    for (int n = lo + threadIdx.x; n < hi; n += 256) acc += nodeval[n];
    __shared__ float red[256];
    red[threadIdx.x] = acc;
    __syncthreads();
    for (int s = 128; s > 0; s >>= 1) {
        if (threadIdx.x < s) red[threadIdx.x] += red[threadIdx.x + s];
        __syncthreads();
    }
    if (threadIdx.x == 0) {
        float cnt = (float)(hi - lo);
        out[g] = red[0] / fmaxf(cnt, 1.0f) + lin_b[0];
    }
}

extern "C" void kernel_launch(void* const* d_in, const int* in_sizes, int n_in,
                              void* d_out, int out_size, void* d_ws, size_t ws_size,
                              hipStream_t stream) {
    const float* x     = (const float*)d_in[0];
    const int*   ei    = (const int*)d_in[1];    // [2,E]: rows then cols
    const int*   batch = (const int*)d_in[2];
    const float* W1    = (const float*)d_in[3];
    const float* b1    = (const float*)d_in[4];
    const float* W2    = (const float*)d_in[5];
    const float* b2    = (const float*)d_in[6];
    const float* W3    = (const float*)d_in[7];
    const float* b3    = (const float*)d_in[8];
    const float* lin_w = (const float*)d_in[9];
    const float* lin_b = (const float*)d_in[10];
    float* out = (float*)d_out;

    const int N = in_sizes[0] / 128;
    const int E = in_sizes[1] / 2;
    const int nBlk = (N + 1023) / 1024;

    // workspace: A | B | deg | dinv | rowptr | src_sorted | scan tmp | nodeval
    float* A         = (float*)d_ws;
    float* B         = A + (size_t)N * 128;
    int*   deg       = (int*)(B + (size_t)N * 128);
    float* dinv      = (float*)(deg + N);
    int*   rowptr    = (int*)(dinv + N);
    int*   src_srt   = rowptr + N;
    int*   blockSums = src_srt + E;
    int*   blockOffs = blockSums + 256;
    float* nodeval   = (float*)(blockOffs + 256);

    // ---- CSR build (once per call, reused by all 3 layers) ----
    hipMemsetAsync(deg, 0, (size_t)N * sizeof(int), stream);
    count_deg_kernel<<<(E + 255) / 256, 256, 0, stream>>>(ei + E, deg, E);
    scan1_kernel<<<nBlk, 256, 0, stream>>>(deg, rowptr, blockSums, N);
    scan2_kernel<<<1, 128, 0, stream>>>(blockSums, blockOffs, nBlk);
    scan3_kernel<<<(N + 255) / 256, 256, 0, stream>>>(rowptr, blockOffs, N);
    dinv_kernel<<<(N + 255) / 256, 256, 0, stream>>>(deg, dinv, N);
    fill_kernel<<<(E + 255) / 256, 256, 0, stream>>>(ei, rowptr, src_srt, E);

    const float* Ws[3] = {W1, W2, W3};
    const float* bs[3] = {b1, b2, b3};
    for (int l = 0; l < 3; ++l) {
        gemm_mfma_kernel<<<(N + 63) / 64, 256, 0, stream>>>(l == 0 ? x : B, Ws[l], A, N,
                                                            l == 0 ? 0 : 1);
        agg_kernel<<<((size_t)N * 64 + 255) / 256, 256, 0, stream>>>(rowptr, src_srt,
                                                                     dinv, A, bs[l], B, N);
    }

    nodedot_kernel<<<((size_t)N * 64 + 255) / 256, 256, 0, stream>>>(B, lin_w, nodeval, N);
    segreduce_kernel<<<64, 256, 0, stream>>>(nodeval, batch, lin_b, out, N);
}

// Round 6
// 806.051 us; speedup vs baseline: 1.0973x; 1.0973x over previous
//
#include <hip/hip_runtime.h>

// ---------------------------------------------------------------------------
// GCN forward, CSR-sorted aggregation (no atomics in hot path):
//   build: deg count -> prefix sum (rowptr) -> counting-sort fill (src_sorted)
//   W prep: split fp32 W -> bf16 hi/lo in MFMA B-fragment order (global, L2-hot)
//   3x: GEMM (bf16-split MFMA, LDS-free, frags from L2) -> agg (float4 gather)
//   pool head: per-node dot -> nodeval[N] -> per-graph segmented block reduce
// All feature matrices [N,128] row-major fp32.
// ---------------------------------------------------------------------------

typedef __attribute__((ext_vector_type(8))) short bf16x8;
typedef __attribute__((ext_vector_type(4))) float f32x4;

__device__ __forceinline__ unsigned short f32_to_bf16_rne(float f) {
    unsigned u = __float_as_uint(f);
    unsigned r = u + 0x7FFF + ((u >> 16) & 1);
    return (unsigned short)(r >> 16);
}
__device__ __forceinline__ float bf16_to_f32(unsigned short h) {
    return __uint_as_float(((unsigned)h) << 16);
}

__global__ __launch_bounds__(256) void count_deg_kernel(const int* __restrict__ col,
                                                        int* __restrict__ deg, int E) {
    int e = blockIdx.x * 256 + threadIdx.x;
    if (e < E) atomicAdd(&deg[col[e]], 1);
}

// per-block exclusive scan of deg (1024 elems/block) -> rowptr; block totals out
__global__ __launch_bounds__(256) void scan1_kernel(const int* __restrict__ deg,
                                                    int* __restrict__ rowptr,
                                                    int* __restrict__ blockSums, int N) {
    __shared__ int ts[256];
    const int t = threadIdx.x;
    const int base = blockIdx.x * 1024 + t * 4;
    int v0 = 0, v1 = 0, v2 = 0, v3 = 0;
    if (base + 3 < N) {
        int4 v = *(const int4*)&deg[base];
        v0 = v.x; v1 = v.y; v2 = v.z; v3 = v.w;
    } else {
        if (base + 0 < N) v0 = deg[base + 0];
        if (base + 1 < N) v1 = deg[base + 1];
        if (base + 2 < N) v2 = deg[base + 2];
        if (base + 3 < N) v3 = deg[base + 3];
    }
    const int tot = v0 + v1 + v2 + v3;
    ts[t] = tot;
    __syncthreads();
    for (int off = 1; off < 256; off <<= 1) {
        int add = (t >= off) ? ts[t - off] : 0;
        __syncthreads();
        ts[t] += add;
        __syncthreads();
    }
    const int excl = ts[t] - tot;
    if (base + 0 < N) rowptr[base + 0] = excl;
    if (base + 1 < N) rowptr[base + 1] = excl + v0;
    if (base + 2 < N) rowptr[base + 2] = excl + v0 + v1;
    if (base + 3 < N) rowptr[base + 3] = excl + v0 + v1 + v2;
    if (t == 255) blockSums[blockIdx.x] = ts[255];
}

__global__ __launch_bounds__(128) void scan2_kernel(const int* __restrict__ blockSums,
                                                    int* __restrict__ blockOffs, int B) {
    __shared__ int ts[128];
    const int t = threadIdx.x;
    ts[t] = (t < B) ? blockSums[t] : 0;
    __syncthreads();
    for (int off = 1; off < 128; off <<= 1) {
        int add = (t >= off) ? ts[t - off] : 0;
        __syncthreads();
        ts[t] += add;
        __syncthreads();
    }
    if (t < B) blockOffs[t] = ts[t];
}

__global__ __launch_bounds__(256) void scan3_kernel(int* __restrict__ rowptr,
                                                    const int* __restrict__ blockOffs, int N) {
    int i = blockIdx.x * 256 + threadIdx.x;
    if (i >= N) return;
    int b = i >> 10;
    if (b > 0) rowptr[i] += blockOffs[b - 1];
}

__global__ __launch_bounds__(256) void dinv_kernel(int* __restrict__ degi,
                                                   float* __restrict__ dinv, int N) {
    int n = blockIdx.x * 256 + threadIdx.x;
    if (n < N) dinv[n] = 1.0f / sqrtf((float)degi[n] + 1.0f);  // +1 = self loop
}

// counting-sort fill; rowptr-shift trick: after fill, bucket c = [rowptr[c-1], rowptr[c])
__global__ __launch_bounds__(256) void fill_kernel(const int* __restrict__ ei,
                                                   int* __restrict__ rowptr,
                                                   int* __restrict__ src_sorted, int E) {
    int e = blockIdx.x * 256 + threadIdx.x;
    if (e >= E) return;
    int c = ei[E + e];
    int pos = atomicAdd(&rowptr[c], 1);
    src_sorted[pos] = ei[e];
}

// split W[128][128] fp32 -> Whi/Wlo u16 in B-fragment order:
// idx = ((c*8+t)*64 + lane)*8 + j  maps to  W[k][n], k=c*32+(lane>>4)*8+j, n=t*16+(lane&15)
__global__ __launch_bounds__(256) void wsplit_kernel(const float* __restrict__ W,
                                                     unsigned short* __restrict__ Whi,
                                                     unsigned short* __restrict__ Wlo) {
    int i = blockIdx.x * 256 + threadIdx.x;   // 16384 total
    int j = i & 7;
    int l = (i >> 3) & 63;
    int t = (i >> 9) & 7;
    int c = i >> 12;
    int k = c * 32 + (l >> 4) * 8 + j;
    int n = t * 16 + (l & 15);
    float v = W[k * 128 + n];
    unsigned short hi = f32_to_bf16_rne(v);
    Whi[i] = hi;
    Wlo[i] = f32_to_bf16_rne(v - bf16_to_f32(hi));
}

// T = act(H) @ W via bf16-split MFMA: T ~= Hhi*Whi + Hhi*Wlo + Hlo*Whi (rel err ~2^-17)
// LDS-free: B-fragments read straight from pre-split global Whi/Wlo (64KB, L2-resident).
// Block = 256 thr = 4 waves, 64 rows (16/wave).
__global__ __launch_bounds__(256) void gemm_mfma_kernel(const float* __restrict__ H,
                                                        const unsigned short* __restrict__ Whi,
                                                        const unsigned short* __restrict__ Wlo,
                                                        float* __restrict__ T,
                                                        int N, int applyRelu) {
    const int tid = threadIdx.x;
    const int wv = tid >> 6;
    const int lane = tid & 63;
    const int r0 = blockIdx.x * 64 + wv * 16;
    const int mrow = lane & 15;
    const int kq = lane >> 4;        // quad
    const int grow = r0 + mrow;
    const bool rok = grow < N;

    f32x4 acc[8];
    #pragma unroll
    for (int t = 0; t < 8; ++t) acc[t] = (f32x4){0.f, 0.f, 0.f, 0.f};

    #pragma unroll
    for (int c = 0; c < 4; ++c) {
        float av[8];
        if (rok) {
            const float4* Hp = (const float4*)(H + (size_t)grow * 128 + c * 32 + kq * 8);
            float4 a0 = Hp[0], a1 = Hp[1];
            av[0] = a0.x; av[1] = a0.y; av[2] = a0.z; av[3] = a0.w;
            av[4] = a1.x; av[5] = a1.y; av[6] = a1.z; av[7] = a1.w;
        } else {
            #pragma unroll
            for (int j = 0; j < 8; ++j) av[j] = 0.f;
        }
        bf16x8 ahi, alo;
        #pragma unroll
        for (int j = 0; j < 8; ++j) {
            float v = av[j];
            if (applyRelu) v = fmaxf(v, 0.f);
            unsigned short h = f32_to_bf16_rne(v);
            unsigned short l = f32_to_bf16_rne(v - bf16_to_f32(h));
            ahi[j] = (short)h;
            alo[j] = (short)l;
        }
        #pragma unroll
        for (int t = 0; t < 8; ++t) {
            const int fidx = (((c * 8 + t) * 64) + lane) * 8;
            bf16x8 wh = *(const bf16x8*)&Whi[fidx];
            bf16x8 wl = *(const bf16x8*)&Wlo[fidx];
            acc[t] = __builtin_amdgcn_mfma_f32_16x16x32_bf16(ahi, wh, acc[t], 0, 0, 0);
            acc[t] = __builtin_amdgcn_mfma_f32_16x16x32_bf16(ahi, wl, acc[t], 0, 0, 0);
            acc[t] = __builtin_amdgcn_mfma_f32_16x16x32_bf16(alo, wh, acc[t], 0, 0, 0);
        }
    }

    // epilogue: C/D layout col=lane&15, row=(lane>>4)*4+r
    #pragma unroll
    for (int r = 0; r < 4; ++r) {
        int orow = r0 + kq * 4 + r;
        if (orow < N) {
            float* Tp = T + (size_t)orow * 128 + mrow;
            #pragma unroll
            for (int t = 0; t < 8; ++t) Tp[t * 16] = acc[t][r];
        }
    }
}

// one wave per node, float4 lanes, 2 edges/iter (lanes 0-31 even, 32-63 odd):
// B[n,:] = dinv[n]^2*A[n,:] + bias + sum_e dinv[n]*dinv[s_e]*A[s_e,:]
__global__ __launch_bounds__(256) void agg_kernel(const int* __restrict__ rowptr,
                                                  const int* __restrict__ src,
                                                  const float* __restrict__ dinv,
                                                  const float* __restrict__ A,
                                                  const float* __restrict__ bias,
                                                  float* __restrict__ B, int N) {
    int w = (blockIdx.x * 256 + threadIdx.x) >> 6;
    if (w >= N) return;
    const int lane = threadIdx.x & 63;
    const int half = lane >> 5;
    const int q = lane & 31;
    const int beg = (w > 0) ? rowptr[w - 1] : 0;
    const int end = rowptr[w];
    const float dn = dinv[w];
    const float4* A4 = (const float4*)A;

    float4 acc = make_float4(0.f, 0.f, 0.f, 0.f);
    for (int e = beg + half; e < end; e += 2) {
        int s = src[e];
        float nrm = dn * dinv[s];
        float4 v = A4[(size_t)s * 32 + q];
        acc.x = fmaf(nrm, v.x, acc.x);
        acc.y = fmaf(nrm, v.y, acc.y);
        acc.z = fmaf(nrm, v.z, acc.z);
        acc.w = fmaf(nrm, v.w, acc.w);
    }
    acc.x += __shfl_xor(acc.x, 32);
    acc.y += __shfl_xor(acc.y, 32);
    acc.z += __shfl_xor(acc.z, 32);
    acc.w += __shfl_xor(acc.w, 32);

    if (half == 0) {
        float4 a = A4[(size_t)w * 32 + q];
        float4 bv = ((const float4*)bias)[q];
        float d2 = dn * dn;
        acc.x = fmaf(d2, a.x, acc.x + bv.x);
        acc.y = fmaf(d2, a.y, acc.y + bv.y);
        acc.z = fmaf(d2, a.z, acc.z + bv.z);
        acc.w = fmaf(d2, a.w, acc.w + bv.w);
        ((float4*)B)[(size_t)w * 32 + q] = acc;
    }
}

// one wave per node: nodeval[n] = dot(relu(H[n,:]), lin_w)  (zero atomics)
__global__ __launch_bounds__(256) void nodedot_kernel(const float* __restrict__ H,
                                                      const float* __restrict__ lin_w,
                                                      float* __restrict__ nodeval, int N) {
    int w = (blockIdx.x * 256 + threadIdx.x) >> 6;
    if (w >= N) return;
    const int lane = threadIdx.x & 63;
    float2 v = ((const float2*)(H + (size_t)w * 128))[lane];
    float2 wv = ((const float2*)lin_w)[lane];
    float s = fmaxf(v.x, 0.f) * wv.x + fmaxf(v.y, 0.f) * wv.y;
    #pragma unroll
    for (int o = 32; o > 0; o >>= 1) s += __shfl_xor(s, o);
    if (lane == 0) nodeval[w] = s;
}

__device__ __forceinline__ int lower_bound_dev(const int* __restrict__ a, int n, int key) {
    int lo = 0, hi = n;
    while (lo < hi) {
        int mid = (lo + hi) >> 1;
        if (a[mid] < key) lo = mid + 1; else hi = mid;
    }
    return lo;
}

// one block per graph: out[g] = mean(nodeval[lo:hi]) + lin_b  (batch is sorted)
__global__ __launch_bounds__(256) void segreduce_kernel(const float* __restrict__ nodeval,
                                                        const int* __restrict__ batch,
                                                        const float* __restrict__ lin_b,
                                                        float* __restrict__ out, int N) {
    const int g = blockIdx.x;
    const int lo = lower_bound_dev(batch, N, g);
    const int hi = lower_bound_dev(batch, N, g + 1);
    float acc = 0.f;
    for (int n = lo + threadIdx.x; n < hi; n += 256) acc += nodeval[n];
    __shared__ float red[256];
    red[threadIdx.x] = acc;
    __syncthreads();
    for (int s = 128; s > 0; s >>= 1) {
        if (threadIdx.x < s) red[threadIdx.x] += red[threadIdx.x + s];
        __syncthreads();
    }
    if (threadIdx.x == 0) {
        float cnt = (float)(hi - lo);
        out[g] = red[0] / fmaxf(cnt, 1.0f) + lin_b[0];
    }
}

extern "C" void kernel_launch(void* const* d_in, const int* in_sizes, int n_in,
                              void* d_out, int out_size, void* d_ws, size_t ws_size,
                              hipStream_t stream) {
    const float* x     = (const float*)d_in[0];
    const int*   ei    = (const int*)d_in[1];    // [2,E]: rows then cols
    const int*   batch = (const int*)d_in[2];
    const float* W1    = (const float*)d_in[3];
    const float* b1    = (const float*)d_in[4];
    const float* W2    = (const float*)d_in[5];
    const float* b2    = (const float*)d_in[6];
    const float* W3    = (const float*)d_in[7];
    const float* b3    = (const float*)d_in[8];
    const float* lin_w = (const float*)d_in[9];
    const float* lin_b = (const float*)d_in[10];
    float* out = (float*)d_out;

    const int N = in_sizes[0] / 128;
    const int E = in_sizes[1] / 2;
    const int nBlk = (N + 1023) / 1024;

    // workspace: A | B | deg | dinv | rowptr | src_sorted | scan tmp | nodeval | Wsplit
    float* A         = (float*)d_ws;
    float* B         = A + (size_t)N * 128;
    int*   deg       = (int*)(B + (size_t)N * 128);
    float* dinv      = (float*)(deg + N);
    int*   rowptr    = (int*)(dinv + N);
    int*   src_srt   = rowptr + N;
    int*   blockSums = src_srt + E;
    int*   blockOffs = blockSums + 256;
    float* nodeval   = (float*)(blockOffs + 256);
    unsigned short* Wfrag = (unsigned short*)(nodeval + N);  // 3 layers x (hi|lo) x 16384

    // ---- CSR build (once per call, reused by all 3 layers) ----
    hipMemsetAsync(deg, 0, (size_t)N * sizeof(int), stream);
    count_deg_kernel<<<(E + 255) / 256, 256, 0, stream>>>(ei + E, deg, E);
    scan1_kernel<<<nBlk, 256, 0, stream>>>(deg, rowptr, blockSums, N);
    scan2_kernel<<<1, 128, 0, stream>>>(blockSums, blockOffs, nBlk);
    scan3_kernel<<<(N + 255) / 256, 256, 0, stream>>>(rowptr, blockOffs, N);
    dinv_kernel<<<(N + 255) / 256, 256, 0, stream>>>(deg, dinv, N);
    fill_kernel<<<(E + 255) / 256, 256, 0, stream>>>(ei, rowptr, src_srt, E);

    const float* Ws[3] = {W1, W2, W3};
    const float* bs[3] = {b1, b2, b3};
    for (int l = 0; l < 3; ++l)
        wsplit_kernel<<<64, 256, 0, stream>>>(Ws[l], Wfrag + l * 32768,
                                              Wfrag + l * 32768 + 16384);

    for (int l = 0; l < 3; ++l) {
        gemm_mfma_kernel<<<(N + 63) / 64, 256, 0, stream>>>(
            l == 0 ? x : B, Wfrag + l * 32768, Wfrag + l * 32768 + 16384, A, N,
            l == 0 ? 0 : 1);
        agg_kernel<<<((size_t)N * 64 + 255) / 256, 256, 0, stream>>>(rowptr, src_srt,
                                                                     dinv, A, bs[l], B, N);
    }

    nodedot_kernel<<<((size_t)N * 64 + 255) / 256, 256, 0, stream>>>(B, lin_w, nodeval, N);
    segreduce_kernel<<<64, 256, 0, stream>>>(nodeval, batch, lin_b, out, N);
}

// Round 7
// 732.642 us; speedup vs baseline: 1.2073x; 1.1002x over previous
//
#include <hip/hip_runtime.h>

// ---------------------------------------------------------------------------
// GCN forward, CSR-sorted aggregation (no atomics in hot path):
//   build: XCD-partitioned deg count -> prefix sum -> XCD-partitioned fill
//   W prep: split fp32 W -> bf16 hi/lo in MFMA B-fragment order (global, L2-hot)
//   3x: GEMM (bf16-split MFMA, LDS-free) -> agg (4-edge-MLP float4 gather)
//   pool head: per-node dot -> nodeval[N] -> per-graph segmented block reduce
// All feature matrices [N,128] row-major fp32.
// ---------------------------------------------------------------------------

typedef __attribute__((ext_vector_type(8))) short bf16x8;
typedef __attribute__((ext_vector_type(4))) float f32x4;

__device__ __forceinline__ unsigned short f32_to_bf16_rne(float f) {
    unsigned u = __float_as_uint(f);
    unsigned r = u + 0x7FFF + ((u >> 16) & 1);
    return (unsigned short)(r >> 16);
}
__device__ __forceinline__ float bf16_to_f32(unsigned short h) {
    return __uint_as_float(((unsigned)h) << 16);
}

// XCD-partitioned degree count: 8 blocks (-> 8 XCDs via round-robin) share each
// edge chunk; block handles only its destination range so atomics stay XCD-local.
__global__ __launch_bounds__(256) void count_deg_kernel(const int* __restrict__ col,
                                                        int* __restrict__ deg,
                                                        int E, int partSize) {
    const int p = blockIdx.x & 7;
    const int e = (blockIdx.x >> 3) * 256 + threadIdx.x;
    if (e >= E) return;
    int c = col[e];
    if (c / partSize == p) atomicAdd(&deg[c], 1);
}

// per-block exclusive scan of deg (1024 elems/block) -> rowptr; block totals out
__global__ __launch_bounds__(256) void scan1_kernel(const int* __restrict__ deg,
                                                    int* __restrict__ rowptr,
                                                    int* __restrict__ blockSums, int N) {
    __shared__ int ts[256];
    const int t = threadIdx.x;
    const int base = blockIdx.x * 1024 + t * 4;
    int v0 = 0, v1 = 0, v2 = 0, v3 = 0;
    if (base + 3 < N) {
        int4 v = *(const int4*)&deg[base];
        v0 = v.x; v1 = v.y; v2 = v.z; v3 = v.w;
    } else {
        if (base + 0 < N) v0 = deg[base + 0];
        if (base + 1 < N) v1 = deg[base + 1];
        if (base + 2 < N) v2 = deg[base + 2];
        if (base + 3 < N) v3 = deg[base + 3];
    }
    const int tot = v0 + v1 + v2 + v3;
    ts[t] = tot;
    __syncthreads();
    for (int off = 1; off < 256; off <<= 1) {
        int add = (t >= off) ? ts[t - off] : 0;
        __syncthreads();
        ts[t] += add;
        __syncthreads();
    }
    const int excl = ts[t] - tot;
    if (base + 0 < N) rowptr[base + 0] = excl;
    if (base + 1 < N) rowptr[base + 1] = excl + v0;
    if (base + 2 < N) rowptr[base + 2] = excl + v0 + v1;
    if (base + 3 < N) rowptr[base + 3] = excl + v0 + v1 + v2;
    if (t == 255) blockSums[blockIdx.x] = ts[255];
}

__global__ __launch_bounds__(128) void scan2_kernel(const int* __restrict__ blockSums,
                                                    int* __restrict__ blockOffs, int B) {
    __shared__ int ts[128];
    const int t = threadIdx.x;
    ts[t] = (t < B) ? blockSums[t] : 0;
    __syncthreads();
    for (int off = 1; off < 128; off <<= 1) {
        int add = (t >= off) ? ts[t - off] : 0;
        __syncthreads();
        ts[t] += add;
        __syncthreads();
    }
    if (t < B) blockOffs[t] = ts[t];
}

__global__ __launch_bounds__(256) void scan3_kernel(int* __restrict__ rowptr,
                                                    const int* __restrict__ blockOffs, int N) {
    int i = blockIdx.x * 256 + threadIdx.x;
    if (i >= N) return;
    int b = i >> 10;
    if (b > 0) rowptr[i] += blockOffs[b - 1];
}

__global__ __launch_bounds__(256) void dinv_kernel(int* __restrict__ degi,
                                                   float* __restrict__ dinv, int N) {
    int n = blockIdx.x * 256 + threadIdx.x;
    if (n < N) dinv[n] = 1.0f / sqrtf((float)degi[n] + 1.0f);  // +1 = self loop
}

// XCD-partitioned counting-sort fill (rowptr-shift trick). 8 blocks share each
// edge chunk; only the block whose destination partition matches writes, so the
// scattered 4B stores and rowptr atomics stay in one XCD's L2 (one writeback/line).
__global__ __launch_bounds__(256) void fill_kernel(const int* __restrict__ ei,
                                                   int* __restrict__ rowptr,
                                                   int* __restrict__ src_sorted,
                                                   int E, int partSize) {
    const int p = blockIdx.x & 7;
    const int e = (blockIdx.x >> 3) * 256 + threadIdx.x;
    if (e >= E) return;
    int c = ei[E + e];
    if (c / partSize != p) return;
    int pos = atomicAdd(&rowptr[c], 1);
    src_sorted[pos] = ei[e];
}

// split W[128][128] fp32 -> Whi/Wlo u16 in B-fragment order:
// idx = ((c*8+t)*64 + lane)*8 + j  maps to  W[k][n], k=c*32+(lane>>4)*8+j, n=t*16+(lane&15)
__global__ __launch_bounds__(256) void wsplit_kernel(const float* __restrict__ W,
                                                     unsigned short* __restrict__ Whi,
                                                     unsigned short* __restrict__ Wlo) {
    int i = blockIdx.x * 256 + threadIdx.x;   // 16384 total
    int j = i & 7;
    int l = (i >> 3) & 63;
    int t = (i >> 9) & 7;
    int c = i >> 12;
    int k = c * 32 + (l >> 4) * 8 + j;
    int n = t * 16 + (l & 15);
    float v = W[k * 128 + n];
    unsigned short hi = f32_to_bf16_rne(v);
    Whi[i] = hi;
    Wlo[i] = f32_to_bf16_rne(v - bf16_to_f32(hi));
}

// T = act(H) @ W via bf16-split MFMA: T ~= Hhi*Whi + Hhi*Wlo + Hlo*Whi (rel err ~2^-17)
// LDS-free: B-fragments read straight from pre-split global Whi/Wlo (64KB, L2-resident).
__global__ __launch_bounds__(256) void gemm_mfma_kernel(const float* __restrict__ H,
                                                        const unsigned short* __restrict__ Whi,
                                                        const unsigned short* __restrict__ Wlo,
                                                        float* __restrict__ T,
                                                        int N, int applyRelu) {
    const int tid = threadIdx.x;
    const int wv = tid >> 6;
    const int lane = tid & 63;
    const int r0 = blockIdx.x * 64 + wv * 16;
    const int mrow = lane & 15;
    const int kq = lane >> 4;        // quad
    const int grow = r0 + mrow;
    const bool rok = grow < N;

    f32x4 acc[8];
    #pragma unroll
    for (int t = 0; t < 8; ++t) acc[t] = (f32x4){0.f, 0.f, 0.f, 0.f};

    #pragma unroll
    for (int c = 0; c < 4; ++c) {
        float av[8];
        if (rok) {
            const float4* Hp = (const float4*)(H + (size_t)grow * 128 + c * 32 + kq * 8);
            float4 a0 = Hp[0], a1 = Hp[1];
            av[0] = a0.x; av[1] = a0.y; av[2] = a0.z; av[3] = a0.w;
            av[4] = a1.x; av[5] = a1.y; av[6] = a1.z; av[7] = a1.w;
        } else {
            #pragma unroll
            for (int j = 0; j < 8; ++j) av[j] = 0.f;
        }
        bf16x8 ahi, alo;
        #pragma unroll
        for (int j = 0; j < 8; ++j) {
            float v = av[j];
            if (applyRelu) v = fmaxf(v, 0.f);
            unsigned short h = f32_to_bf16_rne(v);
            unsigned short l = f32_to_bf16_rne(v - bf16_to_f32(h));
            ahi[j] = (short)h;
            alo[j] = (short)l;
        }
        #pragma unroll
        for (int t = 0; t < 8; ++t) {
            const int fidx = (((c * 8 + t) * 64) + lane) * 8;
            bf16x8 wh = *(const bf16x8*)&Whi[fidx];
            bf16x8 wl = *(const bf16x8*)&Wlo[fidx];
            acc[t] = __builtin_amdgcn_mfma_f32_16x16x32_bf16(ahi, wh, acc[t], 0, 0, 0);
            acc[t] = __builtin_amdgcn_mfma_f32_16x16x32_bf16(ahi, wl, acc[t], 0, 0, 0);
            acc[t] = __builtin_amdgcn_mfma_f32_16x16x32_bf16(alo, wh, acc[t], 0, 0, 0);
        }
    }

    // epilogue: C/D layout col=lane&15, row=(lane>>4)*4+r
    #pragma unroll
    for (int r = 0; r < 4; ++r) {
        int orow = r0 + kq * 4 + r;
        if (orow < N) {
            float* Tp = T + (size_t)orow * 128 + mrow;
            #pragma unroll
            for (int t = 0; t < 8; ++t) Tp[t * 16] = acc[t][r];
        }
    }
}

// one wave per node, 4 edges in flight: lane group g=lane>>4 takes edges beg+g,
// beg+g+4,...; each lane covers 32B (2 x float4) of the 512B row. Groups merged
// via shfl_xor(16/32). B[n,:] = dinv[n]^2*A[n,:] + bias + sum_e dn*dinv[s]*A[s,:]
__global__ __launch_bounds__(256) void agg_kernel(const int* __restrict__ rowptr,
                                                  const int* __restrict__ src,
                                                  const float* __restrict__ dinv,
                                                  const float* __restrict__ A,
                                                  const float* __restrict__ bias,
                                                  float* __restrict__ B, int N) {
    int w = (blockIdx.x * 256 + threadIdx.x) >> 6;
    if (w >= N) return;
    const int lane = threadIdx.x & 63;
    const int g = lane >> 4;           // edge subgroup 0..3
    const int q = lane & 15;           // 32B slot: float4 indices q*2, q*2+1
    const int beg = (w > 0) ? rowptr[w - 1] : 0;
    const int end = rowptr[w];
    const float dn = dinv[w];
    const float4* A4 = (const float4*)A;

    float4 a0 = make_float4(0.f, 0.f, 0.f, 0.f);
    float4 a1 = make_float4(0.f, 0.f, 0.f, 0.f);
    for (int e = beg + g; e < end; e += 4) {
        int s = src[e];
        float nrm = dn * dinv[s];
        float4 v0 = A4[(size_t)s * 32 + q * 2];
        float4 v1 = A4[(size_t)s * 32 + q * 2 + 1];
        a0.x = fmaf(nrm, v0.x, a0.x); a0.y = fmaf(nrm, v0.y, a0.y);
        a0.z = fmaf(nrm, v0.z, a0.z); a0.w = fmaf(nrm, v0.w, a0.w);
        a1.x = fmaf(nrm, v1.x, a1.x); a1.y = fmaf(nrm, v1.y, a1.y);
        a1.z = fmaf(nrm, v1.z, a1.z); a1.w = fmaf(nrm, v1.w, a1.w);
    }
    // merge 4 groups (lanes differing in bits 4,5)
    a0.x += __shfl_xor(a0.x, 16); a0.y += __shfl_xor(a0.y, 16);
    a0.z += __shfl_xor(a0.z, 16); a0.w += __shfl_xor(a0.w, 16);
    a1.x += __shfl_xor(a1.x, 16); a1.y += __shfl_xor(a1.y, 16);
    a1.z += __shfl_xor(a1.z, 16); a1.w += __shfl_xor(a1.w, 16);
    a0.x += __shfl_xor(a0.x, 32); a0.y += __shfl_xor(a0.y, 32);
    a0.z += __shfl_xor(a0.z, 32); a0.w += __shfl_xor(a0.w, 32);
    a1.x += __shfl_xor(a1.x, 32); a1.y += __shfl_xor(a1.y, 32);
    a1.z += __shfl_xor(a1.z, 32); a1.w += __shfl_xor(a1.w, 32);

    if (g == 0) {
        float4 s0 = A4[(size_t)w * 32 + q * 2];
        float4 s1 = A4[(size_t)w * 32 + q * 2 + 1];
        float4 b0 = ((const float4*)bias)[q * 2];
        float4 b1 = ((const float4*)bias)[q * 2 + 1];
        float d2 = dn * dn;
        a0.x = fmaf(d2, s0.x, a0.x + b0.x); a0.y = fmaf(d2, s0.y, a0.y + b0.y);
        a0.z = fmaf(d2, s0.z, a0.z + b0.z); a0.w = fmaf(d2, s0.w, a0.w + b0.w);
        a1.x = fmaf(d2, s1.x, a1.x + b1.x); a1.y = fmaf(d2, s1.y, a1.y + b1.y);
        a1.z = fmaf(d2, s1.z, a1.z + b1.z); a1.w = fmaf(d2, s1.w, a1.w + b1.w);
        ((float4*)B)[(size_t)w * 32 + q * 2]     = a0;
        ((float4*)B)[(size_t)w * 32 + q * 2 + 1] = a1;
    }
}

// one wave per node: nodeval[n] = dot(relu(H[n,:]), lin_w)  (zero atomics)
__global__ __launch_bounds__(256) void nodedot_kernel(const float* __restrict__ H,
                                                      const float* __restrict__ lin_w,
                                                      float* __restrict__ nodeval, int N) {
    int w = (blockIdx.x * 256 + threadIdx.x) >> 6;
    if (w >= N) return;
    const int lane = threadIdx.x & 63;
    float2 v = ((const float2*)(H + (size_t)w * 128))[lane];
    float2 wv = ((const float2*)lin_w)[lane];
    float s = fmaxf(v.x, 0.f) * wv.x + fmaxf(v.y, 0.f) * wv.y;
    #pragma unroll
    for (int o = 32; o > 0; o >>= 1) s += __shfl_xor(s, o);
    if (lane == 0) nodeval[w] = s;
}

__device__ __forceinline__ int lower_bound_dev(const int* __restrict__ a, int n, int key) {
    int lo = 0, hi = n;
    while (lo < hi) {
        int mid = (lo + hi) >> 1;
        if (a[mid] < key) lo = mid + 1; else hi = mid;
    }
    return lo;
}

// one block per graph: out[g] = mean(nodeval[lo:hi]) + lin_b  (batch is sorted)
__global__ __launch_bounds__(256) void segreduce_kernel(const float* __restrict__ nodeval,
                                                        const int* __restrict__ batch,
                                                        const float* __restrict__ lin_b,
                                                        float* __restrict__ out, int N) {
    const int g = blockIdx.x;
    const int lo = lower_bound_dev(batch, N, g);
    const int hi = lower_bound_dev(batch, N, g + 1);
    float acc = 0.f;
    for (int n = lo + threadIdx.x; n < hi; n += 256) acc += nodeval[n];
    __shared__ float red[256];
    red[threadIdx.x] = acc;
    __syncthreads();
    for (int s = 128; s > 0; s >>= 1) {
        if (threadIdx.x < s) red[threadIdx.x] += red[threadIdx.x + s];
        __syncthreads();
    }
    if (threadIdx.x == 0) {
        float cnt = (float)(hi - lo);
        out[g] = red[0] / fmaxf(cnt, 1.0f) + lin_b[0];
    }
}

extern "C" void kernel_launch(void* const* d_in, const int* in_sizes, int n_in,
                              void* d_out, int out_size, void* d_ws, size_t ws_size,
                              hipStream_t stream) {
    const float* x     = (const float*)d_in[0];
    const int*   ei    = (const int*)d_in[1];    // [2,E]: rows then cols
    const int*   batch = (const int*)d_in[2];
    const float* W1    = (const float*)d_in[3];
    const float* b1    = (const float*)d_in[4];
    const float* W2    = (const float*)d_in[5];
    const float* b2    = (const float*)d_in[6];
    const float* W3    = (const float*)d_in[7];
    const float* b3    = (const float*)d_in[8];
    const float* lin_w = (const float*)d_in[9];
    const float* lin_b = (const float*)d_in[10];
    float* out = (float*)d_out;

    const int N = in_sizes[0] / 128;
    const int E = in_sizes[1] / 2;
    const int nBlk = (N + 1023) / 1024;
    const int partSize = (N + 7) / 8;            // XCD destination partition
    const int eChunks = (E + 255) / 256;

    // workspace: A | B | deg | dinv | rowptr | src_sorted | scan tmp | nodeval | Wsplit
    float* A         = (float*)d_ws;
    float* B         = A + (size_t)N * 128;
    int*   deg       = (int*)(B + (size_t)N * 128);
    float* dinv      = (float*)(deg + N);
    int*   rowptr    = (int*)(dinv + N);
    int*   src_srt   = rowptr + N;
    int*   blockSums = src_srt + E;
    int*   blockOffs = blockSums + 256;
    float* nodeval   = (float*)(blockOffs + 256);
    unsigned short* Wfrag = (unsigned short*)(nodeval + N);  // 3 layers x (hi|lo) x 16384

    // ---- CSR build (once per call, reused by all 3 layers) ----
    hipMemsetAsync(deg, 0, (size_t)N * sizeof(int), stream);
    count_deg_kernel<<<8 * eChunks, 256, 0, stream>>>(ei + E, deg, E, partSize);
    scan1_kernel<<<nBlk, 256, 0, stream>>>(deg, rowptr, blockSums, N);
    scan2_kernel<<<1, 128, 0, stream>>>(blockSums, blockOffs, nBlk);
    scan3_kernel<<<(N + 255) / 256, 256, 0, stream>>>(rowptr, blockOffs, N);
    dinv_kernel<<<(N + 255) / 256, 256, 0, stream>>>(deg, dinv, N);
    fill_kernel<<<8 * eChunks, 256, 0, stream>>>(ei, rowptr, src_srt, E, partSize);

    const float* Ws[3] = {W1, W2, W3};
    const float* bs[3] = {b1, b2, b3};
    for (int l = 0; l < 3; ++l)
        wsplit_kernel<<<64, 256, 0, stream>>>(Ws[l], Wfrag + l * 32768,
                                              Wfrag + l * 32768 + 16384);

    for (int l = 0; l < 3; ++l) {
        gemm_mfma_kernel<<<(N + 63) / 64, 256, 0, stream>>>(
            l == 0 ? x : B, Wfrag + l * 32768, Wfrag + l * 32768 + 16384, A, N,
            l == 0 ? 0 : 1);
        agg_kernel<<<((size_t)N * 64 + 255) / 256, 256, 0, stream>>>(rowptr, src_srt,
                                                                     dinv, A, bs[l], B, N);
    }

    nodedot_kernel<<<((size_t)N * 64 + 255) / 256, 256, 0, stream>>>(B, lin_w, nodeval, N);
    segreduce_kernel<<<64, 256, 0, stream>>>(nodeval, batch, lin_b, out, N);
}

// Round 8
// 579.537 us; speedup vs baseline: 1.5262x; 1.2642x over previous
//
#include <hip/hip_runtime.h>

// ---------------------------------------------------------------------------
// GCN forward, CSR-sorted aggregation (no atomics in hot path):
//   build: XCD-partitioned deg count -> prefix sum -> XCD-partitioned fill
//          -> per-edge weight precompute (wgt[e] = dinv[src[e]])
//   W prep: split fp32 W -> bf16 hi/lo in MFMA B-fragment order (global, L2-hot)
//   3x: GEMM (bf16-split MFMA, LDS-free) -> A16 fp16 [N,128]
//       agg (fp16 gather, fp32 accum); layer 3 fuses relu+lin_w dot -> nodeval
//   head: per-graph segmented block reduce over nodeval
// B (post-agg) stays fp32 for GEMM input precision.
// ---------------------------------------------------------------------------

typedef __attribute__((ext_vector_type(8))) short bf16x8;
typedef __attribute__((ext_vector_type(4))) float f32x4;
typedef __attribute__((ext_vector_type(8))) _Float16 half8;

__device__ __forceinline__ unsigned short f32_to_bf16_rne(float f) {
    unsigned u = __float_as_uint(f);
    unsigned r = u + 0x7FFF + ((u >> 16) & 1);
    return (unsigned short)(r >> 16);
}
__device__ __forceinline__ float bf16_to_f32(unsigned short h) {
    return __uint_as_float(((unsigned)h) << 16);
}

// XCD-partitioned degree count: 8 blocks (-> 8 XCDs via round-robin) share each
// edge chunk; block handles only its destination range so atomics stay XCD-local.
__global__ __launch_bounds__(256) void count_deg_kernel(const int* __restrict__ col,
                                                        int* __restrict__ deg,
                                                        int E, int partSize) {
    const int p = blockIdx.x & 7;
    const int e = (blockIdx.x >> 3) * 256 + threadIdx.x;
    if (e >= E) return;
    int c = col[e];
    if (c / partSize == p) atomicAdd(&deg[c], 1);
}

// per-block exclusive scan of deg (1024 elems/block) -> rowptr; block totals out
__global__ __launch_bounds__(256) void scan1_kernel(const int* __restrict__ deg,
                                                    int* __restrict__ rowptr,
                                                    int* __restrict__ blockSums, int N) {
    __shared__ int ts[256];
    const int t = threadIdx.x;
    const int base = blockIdx.x * 1024 + t * 4;
    int v0 = 0, v1 = 0, v2 = 0, v3 = 0;
    if (base + 3 < N) {
        int4 v = *(const int4*)&deg[base];
        v0 = v.x; v1 = v.y; v2 = v.z; v3 = v.w;
    } else {
        if (base + 0 < N) v0 = deg[base + 0];
        if (base + 1 < N) v1 = deg[base + 1];
        if (base + 2 < N) v2 = deg[base + 2];
        if (base + 3 < N) v3 = deg[base + 3];
    }
    const int tot = v0 + v1 + v2 + v3;
    ts[t] = tot;
    __syncthreads();
    for (int off = 1; off < 256; off <<= 1) {
        int add = (t >= off) ? ts[t - off] : 0;
        __syncthreads();
        ts[t] += add;
        __syncthreads();
    }
    const int excl = ts[t] - tot;
    if (base + 0 < N) rowptr[base + 0] = excl;
    if (base + 1 < N) rowptr[base + 1] = excl + v0;
    if (base + 2 < N) rowptr[base + 2] = excl + v0 + v1;
    if (base + 3 < N) rowptr[base + 3] = excl + v0 + v1 + v2;
    if (t == 255) blockSums[blockIdx.x] = ts[255];
}

__global__ __launch_bounds__(128) void scan2_kernel(const int* __restrict__ blockSums,
                                                    int* __restrict__ blockOffs, int B) {
    __shared__ int ts[128];
    const int t = threadIdx.x;
    ts[t] = (t < B) ? blockSums[t] : 0;
    __syncthreads();
    for (int off = 1; off < 128; off <<= 1) {
        int add = (t >= off) ? ts[t - off] : 0;
        __syncthreads();
        ts[t] += add;
        __syncthreads();
    }
    if (t < B) blockOffs[t] = ts[t];
}

__global__ __launch_bounds__(256) void scan3_kernel(int* __restrict__ rowptr,
                                                    const int* __restrict__ blockOffs, int N) {
    int i = blockIdx.x * 256 + threadIdx.x;
    if (i >= N) return;
    int b = i >> 10;
    if (b > 0) rowptr[i] += blockOffs[b - 1];
}

__global__ __launch_bounds__(256) void dinv_kernel(int* __restrict__ degi,
                                                   float* __restrict__ dinv, int N) {
    int n = blockIdx.x * 256 + threadIdx.x;
    if (n < N) dinv[n] = 1.0f / sqrtf((float)degi[n] + 1.0f);  // +1 = self loop
}

// XCD-partitioned counting-sort fill (rowptr-shift trick).
__global__ __launch_bounds__(256) void fill_kernel(const int* __restrict__ ei,
                                                   int* __restrict__ rowptr,
                                                   int* __restrict__ src_sorted,
                                                   int E, int partSize) {
    const int p = blockIdx.x & 7;
    const int e = (blockIdx.x >> 3) * 256 + threadIdx.x;
    if (e >= E) return;
    int c = ei[E + e];
    if (c / partSize != p) return;
    int pos = atomicAdd(&rowptr[c], 1);
    src_sorted[pos] = ei[e];
}

// wgt[e] = dinv[src_sorted[e]]  (dinv is L2-resident; removes dependent load in agg)
__global__ __launch_bounds__(256) void edgew_kernel(const int* __restrict__ src,
                                                    const float* __restrict__ dinv,
                                                    float* __restrict__ wgt, int E) {
    int e = blockIdx.x * 256 + threadIdx.x;
    if (e < E) wgt[e] = dinv[src[e]];
}

// split W[128][128] fp32 -> Whi/Wlo u16 in B-fragment order:
// idx = ((c*8+t)*64 + lane)*8 + j  maps to  W[k][n], k=c*32+(lane>>4)*8+j, n=t*16+(lane&15)
__global__ __launch_bounds__(256) void wsplit_kernel(const float* __restrict__ W,
                                                     unsigned short* __restrict__ Whi,
                                                     unsigned short* __restrict__ Wlo) {
    int i = blockIdx.x * 256 + threadIdx.x;   // 16384 total
    int j = i & 7;
    int l = (i >> 3) & 63;
    int t = (i >> 9) & 7;
    int c = i >> 12;
    int k = c * 32 + (l >> 4) * 8 + j;
    int n = t * 16 + (l & 15);
    float v = W[k * 128 + n];
    unsigned short hi = f32_to_bf16_rne(v);
    Whi[i] = hi;
    Wlo[i] = f32_to_bf16_rne(v - bf16_to_f32(hi));
}

// T16 = fp16( act(H) @ W ) via bf16-split MFMA (rel err ~2^-17 before fp16 store).
// LDS-free: B-fragments read straight from pre-split global Whi/Wlo (64KB, L2-resident).
__global__ __launch_bounds__(256) void gemm_mfma_kernel(const float* __restrict__ H,
                                                        const unsigned short* __restrict__ Whi,
                                                        const unsigned short* __restrict__ Wlo,
                                                        _Float16* __restrict__ T16,
                                                        int N, int applyRelu) {
    const int tid = threadIdx.x;
    const int wv = tid >> 6;
    const int lane = tid & 63;
    const int r0 = blockIdx.x * 64 + wv * 16;
    const int mrow = lane & 15;
    const int kq = lane >> 4;        // quad
    const int grow = r0 + mrow;
    const bool rok = grow < N;

    f32x4 acc[8];
    #pragma unroll
    for (int t = 0; t < 8; ++t) acc[t] = (f32x4){0.f, 0.f, 0.f, 0.f};

    #pragma unroll
    for (int c = 0; c < 4; ++c) {
        float av[8];
        if (rok) {
            const float4* Hp = (const float4*)(H + (size_t)grow * 128 + c * 32 + kq * 8);
            float4 a0 = Hp[0], a1 = Hp[1];
            av[0] = a0.x; av[1] = a0.y; av[2] = a0.z; av[3] = a0.w;
            av[4] = a1.x; av[5] = a1.y; av[6] = a1.z; av[7] = a1.w;
        } else {
            #pragma unroll
            for (int j = 0; j < 8; ++j) av[j] = 0.f;
        }
        bf16x8 ahi, alo;
        #pragma unroll
        for (int j = 0; j < 8; ++j) {
            float v = av[j];
            if (applyRelu) v = fmaxf(v, 0.f);
            unsigned short h = f32_to_bf16_rne(v);
            unsigned short l = f32_to_bf16_rne(v - bf16_to_f32(h));
            ahi[j] = (short)h;
            alo[j] = (short)l;
        }
        #pragma unroll
        for (int t = 0; t < 8; ++t) {
            const int fidx = (((c * 8 + t) * 64) + lane) * 8;
            bf16x8 wh = *(const bf16x8*)&Whi[fidx];
            bf16x8 wl = *(const bf16x8*)&Wlo[fidx];
            acc[t] = __builtin_amdgcn_mfma_f32_16x16x32_bf16(ahi, wh, acc[t], 0, 0, 0);
            acc[t] = __builtin_amdgcn_mfma_f32_16x16x32_bf16(ahi, wl, acc[t], 0, 0, 0);
            acc[t] = __builtin_amdgcn_mfma_f32_16x16x32_bf16(alo, wh, acc[t], 0, 0, 0);
        }
    }

    // epilogue: C/D layout col=lane&15, row=(lane>>4)*4+r; store fp16
    #pragma unroll
    for (int r = 0; r < 4; ++r) {
        int orow = r0 + kq * 4 + r;
        if (orow < N) {
            _Float16* Tp = T16 + (size_t)orow * 128 + mrow;
            #pragma unroll
            for (int t = 0; t < 8; ++t) Tp[t * 16] = (_Float16)acc[t][r];
        }
    }
}

// one wave per node; fp16 rows: 16 lanes/edge x 16B (8 halves), 4 edges in flight.
// acc fp32. mode 0: B[n,:] = d2*A[n,:]+bias+sum (fp32 write).
// mode 1 (layer 3): nodeval[n] = dot(relu(row), lin_w); B not written.
__global__ __launch_bounds__(256) void agg_kernel(const int* __restrict__ rowptr,
                                                  const int* __restrict__ src,
                                                  const float* __restrict__ wgt,
                                                  const float* __restrict__ dinv,
                                                  const _Float16* __restrict__ A16,
                                                  const float* __restrict__ bias,
                                                  float* __restrict__ B,
                                                  const float* __restrict__ lin_w,
                                                  float* __restrict__ nodeval,
                                                  int N, int mode) {
    int w = (blockIdx.x * 256 + threadIdx.x) >> 6;
    if (w >= N) return;
    const int lane = threadIdx.x & 63;
    const int g = lane >> 4;           // edge subgroup 0..3
    const int q = lane & 15;           // 16B slot (8 halves)
    const int beg = (w > 0) ? rowptr[w - 1] : 0;
    const int end = rowptr[w];
    const float dn = dinv[w];
    const half8* A8 = (const half8*)A16;

    float4 a0 = make_float4(0.f, 0.f, 0.f, 0.f);
    float4 a1 = make_float4(0.f, 0.f, 0.f, 0.f);
    for (int e = beg + g; e < end; e += 4) {
        int s = src[e];
        float nrm = dn * wgt[e];
        half8 v = A8[(size_t)s * 16 + q];
        a0.x = fmaf(nrm, (float)v[0], a0.x); a0.y = fmaf(nrm, (float)v[1], a0.y);
        a0.z = fmaf(nrm, (float)v[2], a0.z); a0.w = fmaf(nrm, (float)v[3], a0.w);
        a1.x = fmaf(nrm, (float)v[4], a1.x); a1.y = fmaf(nrm, (float)v[5], a1.y);
        a1.z = fmaf(nrm, (float)v[6], a1.z); a1.w = fmaf(nrm, (float)v[7], a1.w);
    }
    // merge 4 groups (lanes differing in bits 4,5)
    a0.x += __shfl_xor(a0.x, 16); a0.y += __shfl_xor(a0.y, 16);
    a0.z += __shfl_xor(a0.z, 16); a0.w += __shfl_xor(a0.w, 16);
    a1.x += __shfl_xor(a1.x, 16); a1.y += __shfl_xor(a1.y, 16);
    a1.z += __shfl_xor(a1.z, 16); a1.w += __shfl_xor(a1.w, 16);
    a0.x += __shfl_xor(a0.x, 32); a0.y += __shfl_xor(a0.y, 32);
    a0.z += __shfl_xor(a0.z, 32); a0.w += __shfl_xor(a0.w, 32);
    a1.x += __shfl_xor(a1.x, 32); a1.y += __shfl_xor(a1.y, 32);
    a1.z += __shfl_xor(a1.z, 32); a1.w += __shfl_xor(a1.w, 32);

    if (g == 0) {
        half8 sv = A8[(size_t)w * 16 + q];
        float4 b0 = ((const float4*)bias)[q * 2];
        float4 b1 = ((const float4*)bias)[q * 2 + 1];
        float d2 = dn * dn;
        a0.x = fmaf(d2, (float)sv[0], a0.x + b0.x);
        a0.y = fmaf(d2, (float)sv[1], a0.y + b0.y);
        a0.z = fmaf(d2, (float)sv[2], a0.z + b0.z);
        a0.w = fmaf(d2, (float)sv[3], a0.w + b0.w);
        a1.x = fmaf(d2, (float)sv[4], a1.x + b1.x);
        a1.y = fmaf(d2, (float)sv[5], a1.y + b1.y);
        a1.z = fmaf(d2, (float)sv[6], a1.z + b1.z);
        a1.w = fmaf(d2, (float)sv[7], a1.w + b1.w);
        if (mode == 0) {
            ((float4*)B)[(size_t)w * 32 + q * 2]     = a0;
            ((float4*)B)[(size_t)w * 32 + q * 2 + 1] = a1;
        } else {
            float4 w0 = ((const float4*)lin_w)[q * 2];
            float4 w1 = ((const float4*)lin_w)[q * 2 + 1];
            float s = fmaxf(a0.x, 0.f) * w0.x + fmaxf(a0.y, 0.f) * w0.y
                    + fmaxf(a0.z, 0.f) * w0.z + fmaxf(a0.w, 0.f) * w0.w
                    + fmaxf(a1.x, 0.f) * w1.x + fmaxf(a1.y, 0.f) * w1.y
                    + fmaxf(a1.z, 0.f) * w1.z + fmaxf(a1.w, 0.f) * w1.w;
            s += __shfl_xor(s, 1);
            s += __shfl_xor(s, 2);
            s += __shfl_xor(s, 4);
            s += __shfl_xor(s, 8);
            if (q == 0) nodeval[w] = s;
        }
    }
}

__device__ __forceinline__ int lower_bound_dev(const int* __restrict__ a, int n, int key) {
    int lo = 0, hi = n;
    while (lo < hi) {
        int mid = (lo + hi) >> 1;
        if (a[mid] < key) lo = mid + 1; else hi = mid;
    }
    return lo;
}

// one block per graph: out[g] = mean(nodeval[lo:hi]) + lin_b  (batch is sorted)
__global__ __launch_bounds__(256) void segreduce_kernel(const float* __restrict__ nodeval,
                                                        const int* __restrict__ batch,
                                                        const float* __restrict__ lin_b,
                                                        float* __restrict__ out, int N) {
    const int g = blockIdx.x;
    const int lo = lower_bound_dev(batch, N, g);
    const int hi = lower_bound_dev(batch, N, g + 1);
    float acc = 0.f;
    for (int n = lo + threadIdx.x; n < hi; n += 256) acc += nodeval[n];
    __shared__ float red[256];
    red[threadIdx.x] = acc;
    __syncthreads();
    for (int s = 128; s > 0; s >>= 1) {
        if (threadIdx.x < s) red[threadIdx.x] += red[threadIdx.x + s];
        __syncthreads();
    }
    if (threadIdx.x == 0) {
        float cnt = (float)(hi - lo);
        out[g] = red[0] / fmaxf(cnt, 1.0f) + lin_b[0];
    }
}

extern "C" void kernel_launch(void* const* d_in, const int* in_sizes, int n_in,
                              void* d_out, int out_size, void* d_ws, size_t ws_size,
                              hipStream_t stream) {
    const float* x     = (const float*)d_in[0];
    const int*   ei    = (const int*)d_in[1];    // [2,E]: rows then cols
    const int*   batch = (const int*)d_in[2];
    const float* W1    = (const float*)d_in[3];
    const float* b1    = (const float*)d_in[4];
    const float* W2    = (const float*)d_in[5];
    const float* b2    = (const float*)d_in[6];
    const float* W3    = (const float*)d_in[7];
    const float* b3    = (const float*)d_in[8];
    const float* lin_w = (const float*)d_in[9];
    const float* lin_b = (const float*)d_in[10];
    float* out = (float*)d_out;

    const int N = in_sizes[0] / 128;
    const int E = in_sizes[1] / 2;
    const int nBlk = (N + 1023) / 1024;
    const int partSize = (N + 7) / 8;            // XCD destination partition
    const int eChunks = (E + 255) / 256;

    // workspace: A16 | B | deg | dinv | rowptr | src | wgt | scan tmp | nodeval | Wfrag
    _Float16* A16    = (_Float16*)d_ws;
    float* B         = (float*)(A16 + (size_t)N * 128);
    int*   deg       = (int*)(B + (size_t)N * 128);
    float* dinv      = (float*)(deg + N);
    int*   rowptr    = (int*)(dinv + N);
    int*   src_srt   = rowptr + N;
    float* wgt       = (float*)(src_srt + E);
    int*   blockSums = (int*)(wgt + E);
    int*   blockOffs = blockSums + 256;
    float* nodeval   = (float*)(blockOffs + 256);
    unsigned short* Wfrag = (unsigned short*)(nodeval + N);  // 3 layers x (hi|lo) x 16384

    // ---- CSR build (once per call, reused by all 3 layers) ----
    hipMemsetAsync(deg, 0, (size_t)N * sizeof(int), stream);
    count_deg_kernel<<<8 * eChunks, 256, 0, stream>>>(ei + E, deg, E, partSize);
    scan1_kernel<<<nBlk, 256, 0, stream>>>(deg, rowptr, blockSums, N);
    scan2_kernel<<<1, 128, 0, stream>>>(blockSums, blockOffs, nBlk);
    scan3_kernel<<<(N + 255) / 256, 256, 0, stream>>>(rowptr, blockOffs, N);
    dinv_kernel<<<(N + 255) / 256, 256, 0, stream>>>(deg, dinv, N);
    fill_kernel<<<8 * eChunks, 256, 0, stream>>>(ei, rowptr, src_srt, E, partSize);
    edgew_kernel<<<eChunks, 256, 0, stream>>>(src_srt, dinv, wgt, E);

    const float* Ws[3] = {W1, W2, W3};
    const float* bs[3] = {b1, b2, b3};
    for (int l = 0; l < 3; ++l)
        wsplit_kernel<<<64, 256, 0, stream>>>(Ws[l], Wfrag + l * 32768,
                                              Wfrag + l * 32768 + 16384);

    for (int l = 0; l < 3; ++l) {
        gemm_mfma_kernel<<<(N + 63) / 64, 256, 0, stream>>>(
            l == 0 ? x : B, Wfrag + l * 32768, Wfrag + l * 32768 + 16384, A16, N,
            l == 0 ? 0 : 1);
        agg_kernel<<<((size_t)N * 64 + 255) / 256, 256, 0, stream>>>(
            rowptr, src_srt, wgt, dinv, A16, bs[l], B, lin_w, nodeval, N,
            l == 2 ? 1 : 0);
    }

    segreduce_kernel<<<64, 256, 0, stream>>>(nodeval, batch, lin_b, out, N);
}